// Round 1
// baseline (1373.574 us; speedup 1.0000x reference)
//
#include <hip/hip_runtime.h>

#define TSEQ 1024
#define HID_ 1024
#define NH 8
#define DK 128
#define DV 128
#define ROWS 2048               // B*T
#define SZf (ROWS * HID_)       // floats per [2048,1024] matrix

__device__ __forceinline__ float sig_(float x) { return 1.f / (1.f + __expf(-x)); }

// ---------------- 128x128x16 f32 GEMM tile ----------------
__device__ __forceinline__ void sgemm_tile(const float* __restrict__ A,
                                           const float* __restrict__ B,
                                           float* __restrict__ C,
                                           int N, int Kd, int brow, int bcol)
{
    __shared__ float As[16][132];
    __shared__ float Bs[16][132];
    const int tid  = threadIdx.x;
    const int trow = (tid >> 4) << 3;   // (tid/16)*8
    const int tcol = (tid & 15) << 3;   // (tid%16)*8
    const int ar   = tid >> 1;          // 0..127
    const int ac   = (tid & 1) << 3;    // 0 or 8
    const int br   = tid >> 4;          // 0..15
    const int bc   = (tid & 15) << 3;   // 0..120

    float acc[8][8];
#pragma unroll
    for (int i = 0; i < 8; ++i)
#pragma unroll
        for (int j = 0; j < 8; ++j) acc[i][j] = 0.f;

    for (int k0 = 0; k0 < Kd; k0 += 16) {
        float4 a0 = *(const float4*)(A + (size_t)(brow + ar) * Kd + k0 + ac);
        float4 a1 = *(const float4*)(A + (size_t)(brow + ar) * Kd + k0 + ac + 4);
        float4 b0 = *(const float4*)(B + (size_t)(k0 + br) * N + bcol + bc);
        float4 b1 = *(const float4*)(B + (size_t)(k0 + br) * N + bcol + bc + 4);
        As[ac + 0][ar] = a0.x; As[ac + 1][ar] = a0.y; As[ac + 2][ar] = a0.z; As[ac + 3][ar] = a0.w;
        As[ac + 4][ar] = a1.x; As[ac + 5][ar] = a1.y; As[ac + 6][ar] = a1.z; As[ac + 7][ar] = a1.w;
        *(float4*)(&Bs[br][bc])     = b0;
        *(float4*)(&Bs[br][bc + 4]) = b1;
        __syncthreads();
#pragma unroll
        for (int kk = 0; kk < 16; ++kk) {
            float a[8], b[8];
            *(float4*)(a)     = *(const float4*)(&As[kk][trow]);
            *(float4*)(a + 4) = *(const float4*)(&As[kk][trow + 4]);
            *(float4*)(b)     = *(const float4*)(&Bs[kk][tcol]);
            *(float4*)(b + 4) = *(const float4*)(&Bs[kk][tcol + 4]);
#pragma unroll
            for (int i = 0; i < 8; ++i)
#pragma unroll
                for (int j = 0; j < 8; ++j)
                    acc[i][j] = fmaf(a[i], b[j], acc[i][j]);
        }
        __syncthreads();
    }
#pragma unroll
    for (int i = 0; i < 8; ++i) {
        float4 o0 = make_float4(acc[i][0], acc[i][1], acc[i][2], acc[i][3]);
        float4 o1 = make_float4(acc[i][4], acc[i][5], acc[i][6], acc[i][7]);
        *(float4*)(C + (size_t)(brow + trow + i) * N + bcol + tcol)     = o0;
        *(float4*)(C + (size_t)(brow + trow + i) * N + bcol + tcol + 4) = o1;
    }
}

__global__ __launch_bounds__(256)
void k_qkvg_gemm(const float* __restrict__ x,
                 const float* __restrict__ Wq, const float* __restrict__ Wk,
                 const float* __restrict__ Wv, const float* __restrict__ Wg,
                 float* __restrict__ ws)
{
    const float* Bp = (blockIdx.z == 0) ? Wq : (blockIdx.z == 1) ? Wk
                    : (blockIdx.z == 2) ? Wv : Wg;
    float* Cp = ws + (size_t)blockIdx.z * SZf;
    sgemm_tile(x, Bp, Cp, HID_, HID_, blockIdx.y * 128, blockIdx.x * 128);
}

__global__ __launch_bounds__(256)
void k_out_gemm(const float* __restrict__ A, const float* __restrict__ W,
                float* __restrict__ C)
{
    sgemm_tile(A, W, C, HID_, HID_, blockIdx.y * 128, blockIdx.x * 128);
}

// ---------------- alpha/beta small GEMM + sigmoid ----------------
__global__ __launch_bounds__(64)
void k_ab(const float* __restrict__ x, const float* __restrict__ Wa,
          const float* __restrict__ ba, const float* __restrict__ Wb,
          const float* __restrict__ bb, float* __restrict__ alpha,
          float* __restrict__ beta)
{
    const int r = blockIdx.x;
    const int lane = threadIdx.x;
    const float* xr = x + (size_t)r * HID_;
    float acc[16];
#pragma unroll
    for (int n = 0; n < 16; ++n) acc[n] = 0.f;
    for (int c = lane; c < HID_; c += 64) {
        const float xv = xr[c];
        const float* wa = Wa + c * 8;
        const float* wb = Wb + c * 8;
#pragma unroll
        for (int n = 0; n < 8; ++n) {
            acc[n]     = fmaf(xv, wa[n], acc[n]);
            acc[8 + n] = fmaf(xv, wb[n], acc[8 + n]);
        }
    }
#pragma unroll
    for (int n = 0; n < 16; ++n) {
#pragma unroll
        for (int m = 32; m; m >>= 1) acc[n] += __shfl_xor(acc[n], m);
    }
    if (lane < 8) {
        alpha[(size_t)r * 8 + lane] = sig_(acc[lane] + ba[lane]);
        beta[(size_t)r * 8 + lane]  = sig_(acc[8 + lane] + bb[lane]);
    }
}

// -------- causal depthwise conv K=4 + SiLU (+scale), IN-PLACE --------
// grid (HID_/64, B, 3); each block owns 64 channels of one batch for ALL t,
// rolling register window -> in-place safe.
__global__ __launch_bounds__(64)
void k_conv3(float* __restrict__ q, float* __restrict__ k, float* __restrict__ v,
             const float* __restrict__ wq, const float* __restrict__ bq,
             const float* __restrict__ wk, const float* __restrict__ bk,
             const float* __restrict__ wv, const float* __restrict__ bv)
{
    const int z = blockIdx.z;
    float* y          = (z == 0) ? q  : (z == 1) ? k  : v;
    const float* w    = (z == 0) ? wq : (z == 1) ? wk : wv;
    const float* bias = (z == 0) ? bq : (z == 1) ? bk : bv;
    const float scale = (z == 1) ? 0.08838834764831845f : 1.f;  // Dk^-0.5 on k

    const int c = blockIdx.x * 64 + threadIdx.x;
    const int b = blockIdx.y;
    const float w0 = w[c * 4 + 0], w1 = w[c * 4 + 1], w2 = w[c * 4 + 2], w3 = w[c * 4 + 3];
    const float bs = bias[c];
    float y0 = 0.f, y1 = 0.f, y2 = 0.f;
    float* yp = y + (size_t)b * TSEQ * HID_ + c;
#pragma unroll 4
    for (int t = 0; t < TSEQ; ++t) {
        float y3  = yp[(size_t)t * HID_];
        float acc = fmaf(w0, y0, fmaf(w1, y1, fmaf(w2, y2, fmaf(w3, y3, bs))));
        float sv  = acc * sig_(acc) * scale;
        yp[(size_t)t * HID_] = sv;
        y0 = y1; y1 = y2; y2 = y3;
    }
}

// ---------------- sequential scan ----------------
// Rows of S are independent: grid = 16 (b,h) * 4 row-blocks of 32 rows.
// 256 threads: row=tid>>3 (32 rows), oct=tid&7 (8x16 cols). S[16] in regs.
// q/k/v read from in-place conv buffers, layout [b*T+t, h*128+d].
__global__ __launch_bounds__(256)
void k_scan(const float* __restrict__ qlin, const float* __restrict__ klin,
            const float* __restrict__ vlin, const float* __restrict__ alpha,
            const float* __restrict__ beta, float* __restrict__ o)
{
    const int bh  = blockIdx.x >> 2;
    const int rb  = blockIdx.x & 3;
    const int b   = bh >> 3;
    const int h   = bh & 7;
    const int tid = threadIdx.x;
    const int row = tid >> 3;   // 0..31
    const int oct = tid & 7;    // 0..7

    const float* kb = klin + (size_t)b * TSEQ * HID_ + h * DK;
    const float* qb = qlin + (size_t)b * TSEQ * HID_ + h * DK;
    const float* vb = vlin + (size_t)b * TSEQ * HID_ + h * DV + rb * 32;
    const float* ap = alpha + (size_t)b * TSEQ * NH + h;
    const float* bp = beta  + (size_t)b * TSEQ * NH + h;

    __shared__ float kbuf[128], qbuf[128], vbuf[32], sab[2];

    float S[16];
#pragma unroll
    for (int i = 0; i < 16; ++i) S[i] = 0.f;

    float4 pk, pq, pv;
    float pa = 0.f, pb = 0.f;
    if (tid < 32)        pk = ((const float4*)kb)[tid];
    else if (tid < 64)   pq = ((const float4*)qb)[tid & 31];
    else if (tid < 72)   pv = ((const float4*)vb)[tid - 64];
    else if (tid == 72)  { pa = ap[0]; pb = bp[0]; }

#pragma unroll 1
    for (int t = 0; t < TSEQ; ++t) {
        if (tid < 32)        ((float4*)kbuf)[tid] = pk;
        else if (tid < 64)   ((float4*)qbuf)[tid & 31] = pq;
        else if (tid < 72)   ((float4*)vbuf)[tid - 64] = pv;
        else if (tid == 72)  { sab[0] = pa; sab[1] = pb; }
        __syncthreads();
        if (t < TSEQ - 1) {                       // prefetch t+1 under compute
            const int tt = t + 1;
            if (tid < 32)        pk = ((const float4*)(kb + (size_t)tt * HID_))[tid];
            else if (tid < 64)   pq = ((const float4*)(qb + (size_t)tt * HID_))[tid & 31];
            else if (tid < 72)   pv = ((const float4*)(vb + (size_t)tt * HID_))[tid - 64];
            else if (tid == 72)  { pa = ap[(size_t)tt * NH]; pb = bp[(size_t)tt * NH]; }
        }
        const float a_t = sab[0], b_t = sab[1];
        float kr[16];
        float sk = 0.f;
        const float4* k4 = (const float4*)kbuf + (oct << 2);
#pragma unroll
        for (int c = 0; c < 4; ++c) {
            float4 kv = k4[c];
            kr[c * 4 + 0] = kv.x; kr[c * 4 + 1] = kv.y;
            kr[c * 4 + 2] = kv.z; kr[c * 4 + 3] = kv.w;
            sk = fmaf(S[c * 4 + 0], kv.x, sk);
            sk = fmaf(S[c * 4 + 1], kv.y, sk);
            sk = fmaf(S[c * 4 + 2], kv.z, sk);
            sk = fmaf(S[c * 4 + 3], kv.w, sk);
        }
        sk += __shfl_xor(sk, 1); sk += __shfl_xor(sk, 2); sk += __shfl_xor(sk, 4);
        const float err = sk - vbuf[row];
        const float nc1 = -b_t * err;
        float op = 0.f;
        const float4* q4 = (const float4*)qbuf + (oct << 2);
#pragma unroll
        for (int c = 0; c < 4; ++c) {
            float4 qv = q4[c];
            float s;
            s = fmaf(a_t, S[c * 4 + 0], nc1 * kr[c * 4 + 0]); S[c * 4 + 0] = s; op = fmaf(s, qv.x, op);
            s = fmaf(a_t, S[c * 4 + 1], nc1 * kr[c * 4 + 1]); S[c * 4 + 1] = s; op = fmaf(s, qv.y, op);
            s = fmaf(a_t, S[c * 4 + 2], nc1 * kr[c * 4 + 2]); S[c * 4 + 2] = s; op = fmaf(s, qv.z, op);
            s = fmaf(a_t, S[c * 4 + 3], nc1 * kr[c * 4 + 3]); S[c * 4 + 3] = s; op = fmaf(s, qv.w, op);
        }
        op += __shfl_xor(op, 1); op += __shfl_xor(op, 2); op += __shfl_xor(op, 4);
        if (oct == 0)
            o[((size_t)bh * TSEQ + t) * DV + rb * 32 + row] = op;
        __syncthreads();
    }
}

// ---------------- LayerNorm(Dv) + sigmoid gate ----------------
// one wave per (b,t,h) row of 128; o is [B,H,T,Dv]; og is [2048,1024]
__global__ __launch_bounds__(256)
void k_ln_gate(const float* __restrict__ o, const float* __restrict__ g_lin,
               const float* __restrict__ ln_g, const float* __restrict__ ln_b,
               float* __restrict__ og)
{
    const int idx  = blockIdx.x * 4 + (threadIdx.x >> 6);  // 0..16383
    const int lane = threadIdx.x & 63;
    const int h  = idx & 7;
    const int bt = idx >> 3;
    const int b  = bt >> 10;
    const int t  = bt & 1023;
    const float* op = o + ((size_t)(b * NH + h) * TSEQ + t) * DV;
    float2 xv = ((const float2*)op)[lane];
    float s = xv.x + xv.y;
#pragma unroll
    for (int m = 32; m; m >>= 1) s += __shfl_xor(s, m);
    const float mu = s * (1.f / 128.f);
    const float d0 = xv.x - mu, d1 = xv.y - mu;
    float v = d0 * d0 + d1 * d1;
#pragma unroll
    for (int m = 32; m; m >>= 1) v += __shfl_xor(v, m);
    const float inv = rsqrtf(v * (1.f / 128.f) + 1e-5f);
    const int d = lane * 2;
    const float* gp = g_lin + (size_t)bt * HID_ + h * DV;
    const float g0 = sig_(gp[d]), g1 = sig_(gp[d + 1]);
    const float y0 = (d0 * inv * ln_g[d]     + ln_b[d])     * g0;
    const float y1 = (d1 * inv * ln_g[d + 1] + ln_b[d + 1]) * g1;
    ((float2*)(og + (size_t)bt * HID_ + h * DV))[lane] = make_float2(y0, y1);
}

extern "C" void kernel_launch(void* const* d_in, const int* in_sizes, int n_in,
                              void* d_out, int out_size, void* d_ws, size_t ws_size,
                              hipStream_t stream)
{
    const float* x   = (const float*)d_in[0];
    const float* Wq  = (const float*)d_in[1];
    const float* Wk  = (const float*)d_in[2];
    const float* Wv  = (const float*)d_in[3];
    const float* cqw = (const float*)d_in[4];
    const float* cqb = (const float*)d_in[5];
    const float* ckw = (const float*)d_in[6];
    const float* ckb = (const float*)d_in[7];
    const float* cvw = (const float*)d_in[8];
    const float* cvb = (const float*)d_in[9];
    const float* Wa  = (const float*)d_in[10];
    const float* ba  = (const float*)d_in[11];
    const float* Wb  = (const float*)d_in[12];
    const float* bb  = (const float*)d_in[13];
    const float* Wg  = (const float*)d_in[14];
    const float* Wo  = (const float*)d_in[15];
    const float* lng = (const float*)d_in[16];
    const float* lnb = (const float*)d_in[17];
    float* out = (float*)d_out;
    float* ws  = (float*)d_ws;

    float* q_lin = ws;                       // [2048,1024] -> conv'd q in-place
    float* k_lin = ws + 1 * (size_t)SZf;     // conv'd k (pre-scaled)
    float* v_lin = ws + 2 * (size_t)SZf;     // conv'd v
    float* g_lin = ws + 3 * (size_t)SZf;
    float* o_buf = ws + 4 * (size_t)SZf;     // scan out [B,H,T,Dv]
    float* alpha = ws + 5 * (size_t)SZf;
    float* beta  = alpha + ROWS * 8;
    float* og    = ws;                       // reuse q_lin after scan

    k_qkvg_gemm<<<dim3(8, 16, 4), 256, 0, stream>>>(x, Wq, Wk, Wv, Wg, ws);
    k_ab<<<ROWS, 64, 0, stream>>>(x, Wa, ba, Wb, bb, alpha, beta);
    k_conv3<<<dim3(16, 2, 3), 64, 0, stream>>>(q_lin, k_lin, v_lin,
                                               cqw, cqb, ckw, ckb, cvw, cvb);
    k_scan<<<64, 256, 0, stream>>>(q_lin, k_lin, v_lin, alpha, beta, o_buf);
    k_ln_gate<<<4096, 256, 0, stream>>>(o_buf, g_lin, lng, lnb, og);
    k_out_gemm<<<dim3(8, 16), 256, 0, stream>>>(og, Wo, out);
}

// Round 2
// 952.254 us; speedup vs baseline: 1.4424x; 1.4424x over previous
//
#include <hip/hip_runtime.h>

#define TSEQ 1024
#define HID_ 1024
#define NH 8
#define DK 128
#define DV 128
#define ROWS 2048               // B*T
#define SZf (ROWS * HID_)       // floats per [2048,1024] matrix

__device__ __forceinline__ float sig_(float x) { return 1.f / (1.f + __expf(-x)); }

// ---------------- 128x128x16 f32 GEMM tile ----------------
__device__ __forceinline__ void sgemm_tile(const float* __restrict__ A,
                                           const float* __restrict__ B,
                                           float* __restrict__ C,
                                           int N, int Kd, int brow, int bcol)
{
    __shared__ float As[16][132];
    __shared__ float Bs[16][132];
    const int tid  = threadIdx.x;
    const int trow = (tid >> 4) << 3;
    const int tcol = (tid & 15) << 3;
    const int ar   = tid >> 1;
    const int ac   = (tid & 1) << 3;
    const int br   = tid >> 4;
    const int bc   = (tid & 15) << 3;

    float acc[8][8];
#pragma unroll
    for (int i = 0; i < 8; ++i)
#pragma unroll
        for (int j = 0; j < 8; ++j) acc[i][j] = 0.f;

    for (int k0 = 0; k0 < Kd; k0 += 16) {
        float4 a0 = *(const float4*)(A + (size_t)(brow + ar) * Kd + k0 + ac);
        float4 a1 = *(const float4*)(A + (size_t)(brow + ar) * Kd + k0 + ac + 4);
        float4 b0 = *(const float4*)(B + (size_t)(k0 + br) * N + bcol + bc);
        float4 b1 = *(const float4*)(B + (size_t)(k0 + br) * N + bcol + bc + 4);
        As[ac + 0][ar] = a0.x; As[ac + 1][ar] = a0.y; As[ac + 2][ar] = a0.z; As[ac + 3][ar] = a0.w;
        As[ac + 4][ar] = a1.x; As[ac + 5][ar] = a1.y; As[ac + 6][ar] = a1.z; As[ac + 7][ar] = a1.w;
        *(float4*)(&Bs[br][bc])     = b0;
        *(float4*)(&Bs[br][bc + 4]) = b1;
        __syncthreads();
#pragma unroll
        for (int kk = 0; kk < 16; ++kk) {
            float a[8], b[8];
            *(float4*)(a)     = *(const float4*)(&As[kk][trow]);
            *(float4*)(a + 4) = *(const float4*)(&As[kk][trow + 4]);
            *(float4*)(b)     = *(const float4*)(&Bs[kk][tcol]);
            *(float4*)(b + 4) = *(const float4*)(&Bs[kk][tcol + 4]);
#pragma unroll
            for (int i = 0; i < 8; ++i)
#pragma unroll
                for (int j = 0; j < 8; ++j)
                    acc[i][j] = fmaf(a[i], b[j], acc[i][j]);
        }
        __syncthreads();
    }
#pragma unroll
    for (int i = 0; i < 8; ++i) {
        float4 o0 = make_float4(acc[i][0], acc[i][1], acc[i][2], acc[i][3]);
        float4 o1 = make_float4(acc[i][4], acc[i][5], acc[i][6], acc[i][7]);
        *(float4*)(C + (size_t)(brow + trow + i) * N + bcol + tcol)     = o0;
        *(float4*)(C + (size_t)(brow + trow + i) * N + bcol + tcol + 4) = o1;
    }
}

__global__ __launch_bounds__(256)
void k_qkvg_gemm(const float* __restrict__ x,
                 const float* __restrict__ Wq, const float* __restrict__ Wk,
                 const float* __restrict__ Wv, const float* __restrict__ Wg,
                 float* __restrict__ ws)
{
    const float* Bp = (blockIdx.z == 0) ? Wq : (blockIdx.z == 1) ? Wk
                    : (blockIdx.z == 2) ? Wv : Wg;
    float* Cp = ws + (size_t)blockIdx.z * SZf;
    sgemm_tile(x, Bp, Cp, HID_, HID_, blockIdx.y * 128, blockIdx.x * 128);
}

__global__ __launch_bounds__(256)
void k_out_gemm(const float* __restrict__ A, const float* __restrict__ W,
                float* __restrict__ C)
{
    sgemm_tile(A, W, C, HID_, HID_, blockIdx.y * 128, blockIdx.x * 128);
}

// -------- alpha/beta small GEMM + sigmoid; writes TRANSPOSED [bh][t] --------
__global__ __launch_bounds__(64)
void k_ab(const float* __restrict__ x, const float* __restrict__ Wa,
          const float* __restrict__ ba, const float* __restrict__ Wb,
          const float* __restrict__ bb, float* __restrict__ aT,
          float* __restrict__ bT)
{
    const int r = blockIdx.x;           // r = b*1024 + t
    const int lane = threadIdx.x;
    const int b = r >> 10, t = r & 1023;
    const float* xr = x + (size_t)r * HID_;
    float acc[16];
#pragma unroll
    for (int n = 0; n < 16; ++n) acc[n] = 0.f;
    for (int c = lane; c < HID_; c += 64) {
        const float xv = xr[c];
        const float* wa = Wa + c * 8;
        const float* wb = Wb + c * 8;
#pragma unroll
        for (int n = 0; n < 8; ++n) {
            acc[n]     = fmaf(xv, wa[n], acc[n]);
            acc[8 + n] = fmaf(xv, wb[n], acc[8 + n]);
        }
    }
#pragma unroll
    for (int n = 0; n < 16; ++n) {
#pragma unroll
        for (int m = 32; m; m >>= 1) acc[n] += __shfl_xor(acc[n], m);
    }
    if (lane < 8) {
        aT[(size_t)(b * 8 + lane) * TSEQ + t] = sig_(acc[lane] + ba[lane]);
        bT[(size_t)(b * 8 + lane) * TSEQ + t] = sig_(acc[8 + lane] + bb[lane]);
    }
}

// -------- causal depthwise conv K=4 + SiLU (+scale), in-place, T-parallel ----
// pass 1: save the 3 boundary rows before each 64-step chunk (pre-conv values)
__global__ __launch_bounds__(256)
void k_conv_save(const float* __restrict__ q, const float* __restrict__ k,
                 const float* __restrict__ v, float* __restrict__ scr)
{
    const int z = blockIdx.z, b = blockIdx.y, j = blockIdx.x + 1;  // j=1..15
    const float* y = (z == 0) ? q : (z == 1) ? k : v;
    float* d = scr + ((size_t)(z * 2 + b) * 15 + (j - 1)) * 3 * 1024;
    const float* s = y + ((size_t)b * TSEQ + j * 64 - 3) * HID_;
    for (int i = threadIdx.x; i < 3 * 1024; i += 256)
        d[i] = s[i];
}

// pass 2: each block = (time-chunk j, channel-group, b, tensor z); in-place.
__global__ __launch_bounds__(256)
void k_conv_apply(float* __restrict__ q, float* __restrict__ k, float* __restrict__ v,
                  const float* __restrict__ scr,
                  const float* __restrict__ wq, const float* __restrict__ bq,
                  const float* __restrict__ wk, const float* __restrict__ bk,
                  const float* __restrict__ wv, const float* __restrict__ bv)
{
    const int z = blockIdx.z, b = blockIdx.y;
    const int j = blockIdx.x >> 2, cg = blockIdx.x & 3;
    float* y          = (z == 0) ? q  : (z == 1) ? k  : v;
    const float* w    = (z == 0) ? wq : (z == 1) ? wk : wv;
    const float* bias = (z == 0) ? bq : (z == 1) ? bk : bv;
    const float scale = (z == 1) ? 0.08838834764831845f : 1.f;  // Dk^-0.5 on k
    const int c = cg * 256 + threadIdx.x;
    const float w0 = w[c * 4], w1 = w[c * 4 + 1], w2 = w[c * 4 + 2], w3 = w[c * 4 + 3];
    const float bs = bias[c];
    float y0 = 0.f, y1 = 0.f, y2 = 0.f;
    if (j > 0) {
        const float* s = scr + ((size_t)(z * 2 + b) * 15 + (j - 1)) * 3 * 1024 + c;
        y0 = s[0]; y1 = s[1024]; y2 = s[2048];
    }
    float* yp = y + ((size_t)b * TSEQ + j * 64) * HID_ + c;
#pragma unroll 4
    for (int t = 0; t < 64; ++t) {
        float y3  = yp[(size_t)t * HID_];
        float acc = fmaf(w0, y0, fmaf(w1, y1, fmaf(w2, y2, fmaf(w3, y3, bs))));
        float sv  = acc * sig_(acc) * scale;
        yp[(size_t)t * HID_] = sv;
        y0 = y1; y1 = y2; y2 = y3;
    }
}

// ---------------- sequential scan, chunked staging ----------------
// 64 blocks = 16 (b,h) x 4 row-blocks of 32 rows; 256 thr: row=tid>>3, oct=tid&7.
// S[16] per thread. Per chunk of 16 steps: stage k/q/v/a/b to LDS (double-buffered,
// loads issued one chunk ahead, held in regs, ds_write before the single barrier).
// Inner 16 steps: LDS reads (imm offsets) + shuffles only -> no barriers.
#define SCH 16
#define NCH (TSEQ / SCH)
#define NF4 1160                 // float4s per chunk: K 512 | Q 512 | V 128 | A 4 | B 4
#define QOFF 2048
#define VOFF 4096
#define AOFF 4608
#define BOFF 4624
#define CBUF 4640

__global__ __launch_bounds__(256)
void k_scan(const float* __restrict__ qlin, const float* __restrict__ klin,
            const float* __restrict__ vlin, const float* __restrict__ aT,
            const float* __restrict__ bT, float* __restrict__ o)
{
    const int bh  = blockIdx.x >> 2;
    const int rb  = blockIdx.x & 3;
    const int b   = bh >> 3;
    const int h   = bh & 7;
    const int tid = threadIdx.x;
    const int row = tid >> 3;
    const int oct = tid & 7;

    const float* kbase = klin + (size_t)b * TSEQ * HID_ + h * DK;
    const float* qbase = qlin + (size_t)b * TSEQ * HID_ + h * DK;
    const float* vbase = vlin + (size_t)b * TSEQ * HID_ + h * DV + rb * 32;
    const float* ap = aT + (size_t)bh * TSEQ;
    const float* bp = bT + (size_t)bh * TSEQ;

    __shared__ float chunk[2][CBUF];

    // per-thread staging descriptors: 5 float4 slots
    const float* srcp[5];
    int strd[5], dof[5];
    bool val[5];
#pragma unroll
    for (int j = 0; j < 5; ++j) {
        const int i4 = j * 256 + tid;
        val[j] = (i4 < NF4);
        dof[j] = i4 * 4;
        const float* s = kbase; int st = 0;
        if (i4 < 512)       { s = kbase + (size_t)(i4 >> 5) * HID_ + ((i4 & 31) << 2); st = SCH * HID_; }
        else if (i4 < 1024) { int m = i4 - 512;  s = qbase + (size_t)(m >> 5) * HID_ + ((m & 31) << 2); st = SCH * HID_; }
        else if (i4 < 1152) { int m = i4 - 1024; s = vbase + (size_t)(m >> 3) * HID_ + ((m & 7) << 2); st = SCH * HID_; }
        else if (i4 < 1156) { s = ap + ((i4 - 1152) << 2); st = SCH; }
        else                { s = bp + ((i4 - 1156) << 2); st = SCH; }
        srcp[j] = s; strd[j] = st;
    }

    float S[16];
#pragma unroll
    for (int i = 0; i < 16; ++i) S[i] = 0.f;

    float4 r[5];
    // prologue: chunk 0 -> buf 0
#pragma unroll
    for (int j = 0; j < 5; ++j)
        if (val[j]) r[j] = *(const float4*)(srcp[j]);
#pragma unroll
    for (int j = 0; j < 5; ++j)
        if (val[j]) *(float4*)(&chunk[0][dof[j]]) = r[j];
    __syncthreads();

    float* optr = o + (size_t)bh * TSEQ * DV + rb * 32 + row;

    for (int c = 0; c < NCH; ++c) {
        const int cur = c & 1;
        if (c + 1 < NCH) {      // issue next chunk's loads; held in regs thru compute
#pragma unroll
            for (int j = 0; j < 5; ++j)
                if (val[j]) r[j] = *(const float4*)(srcp[j] + (size_t)(c + 1) * strd[j]);
        }
        const float* cb = chunk[cur];
        const int t0 = c * SCH;
#pragma unroll
        for (int t = 0; t < SCH; ++t) {
            const float4 k0 = *(const float4*)(cb + t * 128 + oct * 16);
            const float4 k1 = *(const float4*)(cb + t * 128 + oct * 16 + 4);
            const float4 k2 = *(const float4*)(cb + t * 128 + oct * 16 + 8);
            const float4 k3 = *(const float4*)(cb + t * 128 + oct * 16 + 12);
            float a0 = fmaf(S[0],  k0.x, fmaf(S[1],  k0.y, fmaf(S[2],  k0.z, S[3]  * k0.w)));
            float a1 = fmaf(S[4],  k1.x, fmaf(S[5],  k1.y, fmaf(S[6],  k1.z, S[7]  * k1.w)));
            float a2 = fmaf(S[8],  k2.x, fmaf(S[9],  k2.y, fmaf(S[10], k2.z, S[11] * k2.w)));
            float a3 = fmaf(S[12], k3.x, fmaf(S[13], k3.y, fmaf(S[14], k3.z, S[15] * k3.w)));
            float sk = (a0 + a1) + (a2 + a3);
            sk += __shfl_xor(sk, 1);
            sk += __shfl_xor(sk, 2);
            sk += __shfl_xor(sk, 4);
            const float vt  = cb[VOFF + t * 32 + row];
            const float at  = cb[AOFF + t];
            const float btv = cb[BOFF + t];
            const float nc1 = -btv * (sk - vt);
            const float4 q0 = *(const float4*)(cb + QOFF + t * 128 + oct * 16);
            const float4 q1 = *(const float4*)(cb + QOFF + t * 128 + oct * 16 + 4);
            const float4 q2 = *(const float4*)(cb + QOFF + t * 128 + oct * 16 + 8);
            const float4 q3 = *(const float4*)(cb + QOFF + t * 128 + oct * 16 + 12);
            S[0]  = fmaf(at, S[0],  nc1 * k0.x);
            S[1]  = fmaf(at, S[1],  nc1 * k0.y);
            S[2]  = fmaf(at, S[2],  nc1 * k0.z);
            S[3]  = fmaf(at, S[3],  nc1 * k0.w);
            S[4]  = fmaf(at, S[4],  nc1 * k1.x);
            S[5]  = fmaf(at, S[5],  nc1 * k1.y);
            S[6]  = fmaf(at, S[6],  nc1 * k1.z);
            S[7]  = fmaf(at, S[7],  nc1 * k1.w);
            S[8]  = fmaf(at, S[8],  nc1 * k2.x);
            S[9]  = fmaf(at, S[9],  nc1 * k2.y);
            S[10] = fmaf(at, S[10], nc1 * k2.z);
            S[11] = fmaf(at, S[11], nc1 * k2.w);
            S[12] = fmaf(at, S[12], nc1 * k3.x);
            S[13] = fmaf(at, S[13], nc1 * k3.y);
            S[14] = fmaf(at, S[14], nc1 * k3.z);
            S[15] = fmaf(at, S[15], nc1 * k3.w);
            float o0 = fmaf(S[0],  q0.x, fmaf(S[1],  q0.y, fmaf(S[2],  q0.z, S[3]  * q0.w)));
            float o1 = fmaf(S[4],  q1.x, fmaf(S[5],  q1.y, fmaf(S[6],  q1.z, S[7]  * q1.w)));
            float o2 = fmaf(S[8],  q2.x, fmaf(S[9],  q2.y, fmaf(S[10], q2.z, S[11] * q2.w)));
            float o3 = fmaf(S[12], q3.x, fmaf(S[13], q3.y, fmaf(S[14], q3.z, S[15] * q3.w)));
            float opv = (o0 + o1) + (o2 + o3);
            opv += __shfl_xor(opv, 1);
            opv += __shfl_xor(opv, 2);
            opv += __shfl_xor(opv, 4);
            if (oct == 0) optr[(size_t)(t0 + t) * DV] = opv;
        }
        if (c + 1 < NCH) {      // land next chunk into the other buffer
            float* wbf = (float*)chunk[cur ^ 1];
#pragma unroll
            for (int j = 0; j < 5; ++j)
                if (val[j]) *(float4*)(wbf + dof[j]) = r[j];
        }
        __syncthreads();        // one barrier per 16 steps
    }
}

// ---------------- LayerNorm(Dv) + sigmoid gate ----------------
__global__ __launch_bounds__(256)
void k_ln_gate(const float* __restrict__ o, const float* __restrict__ g_lin,
               const float* __restrict__ ln_g, const float* __restrict__ ln_b,
               float* __restrict__ og)
{
    const int idx  = blockIdx.x * 4 + (threadIdx.x >> 6);
    const int lane = threadIdx.x & 63;
    const int h  = idx & 7;
    const int bt = idx >> 3;
    const int b  = bt >> 10;
    const int t  = bt & 1023;
    const float* op = o + ((size_t)(b * NH + h) * TSEQ + t) * DV;
    float2 xv = ((const float2*)op)[lane];
    float s = xv.x + xv.y;
#pragma unroll
    for (int m = 32; m; m >>= 1) s += __shfl_xor(s, m);
    const float mu = s * (1.f / 128.f);
    const float d0 = xv.x - mu, d1 = xv.y - mu;
    float v = d0 * d0 + d1 * d1;
#pragma unroll
    for (int m = 32; m; m >>= 1) v += __shfl_xor(v, m);
    const float inv = rsqrtf(v * (1.f / 128.f) + 1e-5f);
    const int d = lane * 2;
    const float* gp = g_lin + (size_t)bt * HID_ + h * DV;
    const float g0 = sig_(gp[d]), g1 = sig_(gp[d + 1]);
    const float y0 = (d0 * inv * ln_g[d]     + ln_b[d])     * g0;
    const float y1 = (d1 * inv * ln_g[d + 1] + ln_b[d + 1]) * g1;
    ((float2*)(og + (size_t)bt * HID_ + h * DV))[lane] = make_float2(y0, y1);
}

extern "C" void kernel_launch(void* const* d_in, const int* in_sizes, int n_in,
                              void* d_out, int out_size, void* d_ws, size_t ws_size,
                              hipStream_t stream)
{
    const float* x   = (const float*)d_in[0];
    const float* Wq  = (const float*)d_in[1];
    const float* Wk  = (const float*)d_in[2];
    const float* Wv  = (const float*)d_in[3];
    const float* cqw = (const float*)d_in[4];
    const float* cqb = (const float*)d_in[5];
    const float* ckw = (const float*)d_in[6];
    const float* ckb = (const float*)d_in[7];
    const float* cvw = (const float*)d_in[8];
    const float* cvb = (const float*)d_in[9];
    const float* Wa  = (const float*)d_in[10];
    const float* ba  = (const float*)d_in[11];
    const float* Wb  = (const float*)d_in[12];
    const float* bb  = (const float*)d_in[13];
    const float* Wg  = (const float*)d_in[14];
    const float* Wo  = (const float*)d_in[15];
    const float* lng = (const float*)d_in[16];
    const float* lnb = (const float*)d_in[17];
    float* out = (float*)d_out;
    float* ws  = (float*)d_ws;

    float* q_lin = ws;                       // conv'd in place
    float* k_lin = ws + 1 * (size_t)SZf;     // conv'd + pre-scaled in place
    float* v_lin = ws + 2 * (size_t)SZf;
    float* g_lin = ws + 3 * (size_t)SZf;
    float* o_buf = ws + 4 * (size_t)SZf;     // also conv boundary scratch (before scan)
    float* aT    = ws + 5 * (size_t)SZf;     // [bh][t]
    float* bT    = aT + 16 * TSEQ;
    float* og    = ws;                       // reuse q_lin after scan

    k_qkvg_gemm<<<dim3(8, 16, 4), 256, 0, stream>>>(x, Wq, Wk, Wv, Wg, ws);
    k_ab<<<ROWS, 64, 0, stream>>>(x, Wa, ba, Wb, bb, aT, bT);
    k_conv_save<<<dim3(15, 2, 3), 256, 0, stream>>>(q_lin, k_lin, v_lin, o_buf);
    k_conv_apply<<<dim3(64, 2, 3), 256, 0, stream>>>(q_lin, k_lin, v_lin, o_buf,
                                                     cqw, cqb, ckw, ckb, cvw, cvb);
    k_scan<<<64, 256, 0, stream>>>(q_lin, k_lin, v_lin, aT, bT, o_buf);
    k_ln_gate<<<4096, 256, 0, stream>>>(o_buf, g_lin, lng, lnb, og);
    k_out_gemm<<<dim3(8, 16), 256, 0, stream>>>(og, Wo, out);
}

// Round 4
// 794.904 us; speedup vs baseline: 1.7280x; 1.1979x over previous
//
#include <hip/hip_runtime.h>

#define TSEQ 1024
#define HID_ 1024
#define NH 8
#define DK 128
#define DV 128
#define ROWS 2048               // B*T
#define SZf (ROWS * HID_)       // floats per [2048,1024] matrix

__device__ __forceinline__ float sig_(float x) { return 1.f / (1.f + __expf(-x)); }

// ---- 8-lane butterfly reduce at VALU speed via DPP (no LDS pipe, no waitcnt)
// masks {1,2,7}: quad_perm[1,0,3,2]=0xB1, quad_perm[2,3,0,1]=0x4E, row_half_mirror=0x141
template<int CTRL>
__device__ __forceinline__ float dpp_add(float x) {
    int yi = __builtin_amdgcn_update_dpp(0, __builtin_bit_cast(int, x),
                                         CTRL, 0xF, 0xF, true);
    return x + __builtin_bit_cast(float, yi);
}
__device__ __forceinline__ float reduce8_dpp(float x) {
    x = dpp_add<0xB1>(x);
    x = dpp_add<0x4E>(x);
    x = dpp_add<0x141>(x);
    return x;
}

// ---------------- 128x128x16 f32 GEMM tile ----------------
__device__ __forceinline__ void sgemm_tile(const float* __restrict__ A,
                                           const float* __restrict__ B,
                                           float* __restrict__ C,
                                           int N, int Kd, int brow, int bcol)
{
    __shared__ float As[16][132];
    __shared__ float Bs[16][132];
    const int tid  = threadIdx.x;
    const int trow = (tid >> 4) << 3;
    const int tcol = (tid & 15) << 3;
    const int ar   = tid >> 1;
    const int ac   = (tid & 1) << 3;
    const int br   = tid >> 4;
    const int bc   = (tid & 15) << 3;

    float acc[8][8];
#pragma unroll
    for (int i = 0; i < 8; ++i)
#pragma unroll
        for (int j = 0; j < 8; ++j) acc[i][j] = 0.f;

    for (int k0 = 0; k0 < Kd; k0 += 16) {
        float4 a0 = *(const float4*)(A + (size_t)(brow + ar) * Kd + k0 + ac);
        float4 a1 = *(const float4*)(A + (size_t)(brow + ar) * Kd + k0 + ac + 4);
        float4 b0 = *(const float4*)(B + (size_t)(k0 + br) * N + bcol + bc);
        float4 b1 = *(const float4*)(B + (size_t)(k0 + br) * N + bcol + bc + 4);
        As[ac + 0][ar] = a0.x; As[ac + 1][ar] = a0.y; As[ac + 2][ar] = a0.z; As[ac + 3][ar] = a0.w;
        As[ac + 4][ar] = a1.x; As[ac + 5][ar] = a1.y; As[ac + 6][ar] = a1.z; As[ac + 7][ar] = a1.w;
        *(float4*)(&Bs[br][bc])     = b0;
        *(float4*)(&Bs[br][bc + 4]) = b1;
        __syncthreads();
#pragma unroll
        for (int kk = 0; kk < 16; ++kk) {
            float a[8], b[8];
            *(float4*)(a)     = *(const float4*)(&As[kk][trow]);
            *(float4*)(a + 4) = *(const float4*)(&As[kk][trow + 4]);
            *(float4*)(b)     = *(const float4*)(&Bs[kk][tcol]);
            *(float4*)(b + 4) = *(const float4*)(&Bs[kk][tcol + 4]);
#pragma unroll
            for (int i = 0; i < 8; ++i)
#pragma unroll
                for (int j = 0; j < 8; ++j)
                    acc[i][j] = fmaf(a[i], b[j], acc[i][j]);
        }
        __syncthreads();
    }
#pragma unroll
    for (int i = 0; i < 8; ++i) {
        float4 o0 = make_float4(acc[i][0], acc[i][1], acc[i][2], acc[i][3]);
        float4 o1 = make_float4(acc[i][4], acc[i][5], acc[i][6], acc[i][7]);
        *(float4*)(C + (size_t)(brow + trow + i) * N + bcol + tcol)     = o0;
        *(float4*)(C + (size_t)(brow + trow + i) * N + bcol + tcol + 4) = o1;
    }
}

__global__ __launch_bounds__(256)
void k_qkvg_gemm(const float* __restrict__ x,
                 const float* __restrict__ Wq, const float* __restrict__ Wk,
                 const float* __restrict__ Wv, const float* __restrict__ Wg,
                 float* __restrict__ ws)
{
    const float* Bp = (blockIdx.z == 0) ? Wq : (blockIdx.z == 1) ? Wk
                    : (blockIdx.z == 2) ? Wv : Wg;
    float* Cp = ws + (size_t)blockIdx.z * SZf;
    sgemm_tile(x, Bp, Cp, HID_, HID_, blockIdx.y * 128, blockIdx.x * 128);
}

__global__ __launch_bounds__(256)
void k_out_gemm(const float* __restrict__ A, const float* __restrict__ W,
                float* __restrict__ C)
{
    sgemm_tile(A, W, C, HID_, HID_, blockIdx.y * 128, blockIdx.x * 128);
}

// -------- alpha/beta small GEMM + sigmoid; writes TRANSPOSED [bh][t] --------
__global__ __launch_bounds__(64)
void k_ab(const float* __restrict__ x, const float* __restrict__ Wa,
          const float* __restrict__ ba, const float* __restrict__ Wb,
          const float* __restrict__ bb, float* __restrict__ aT,
          float* __restrict__ bT)
{
    const int r = blockIdx.x;           // r = b*1024 + t
    const int lane = threadIdx.x;
    const int b = r >> 10, t = r & 1023;
    const float* xr = x + (size_t)r * HID_;
    float acc[16];
#pragma unroll
    for (int n = 0; n < 16; ++n) acc[n] = 0.f;
    for (int c = lane; c < HID_; c += 64) {
        const float xv = xr[c];
        const float* wa = Wa + c * 8;
        const float* wb = Wb + c * 8;
#pragma unroll
        for (int n = 0; n < 8; ++n) {
            acc[n]     = fmaf(xv, wa[n], acc[n]);
            acc[8 + n] = fmaf(xv, wb[n], acc[8 + n]);
        }
    }
#pragma unroll
    for (int n = 0; n < 16; ++n) {
#pragma unroll
        for (int m = 32; m; m >>= 1) acc[n] += __shfl_xor(acc[n], m);
    }
    if (lane < 8) {
        aT[(size_t)(b * 8 + lane) * TSEQ + t] = sig_(acc[lane] + ba[lane]);
        bT[(size_t)(b * 8 + lane) * TSEQ + t] = sig_(acc[8 + lane] + bb[lane]);
    }
}

// -------- causal depthwise conv K=4 + SiLU (+scale), in-place, T-parallel ----
__global__ __launch_bounds__(256)
void k_conv_save(const float* __restrict__ q, const float* __restrict__ k,
                 const float* __restrict__ v, float* __restrict__ scr)
{
    const int z = blockIdx.z, b = blockIdx.y, j = blockIdx.x + 1;  // j=1..15
    const float* y = (z == 0) ? q : (z == 1) ? k : v;
    float* d = scr + ((size_t)(z * 2 + b) * 15 + (j - 1)) * 3 * 1024;
    const float* s = y + ((size_t)b * TSEQ + j * 64 - 3) * HID_;
    for (int i = threadIdx.x; i < 3 * 1024; i += 256)
        d[i] = s[i];
}

__global__ __launch_bounds__(256)
void k_conv_apply(float* __restrict__ q, float* __restrict__ k, float* __restrict__ v,
                  const float* __restrict__ scr,
                  const float* __restrict__ wq, const float* __restrict__ bq,
                  const float* __restrict__ wk, const float* __restrict__ bk,
                  const float* __restrict__ wv, const float* __restrict__ bv)
{
    const int z = blockIdx.z, b = blockIdx.y;
    const int j = blockIdx.x >> 2, cg = blockIdx.x & 3;
    float* y          = (z == 0) ? q  : (z == 1) ? k  : v;
    const float* w    = (z == 0) ? wq : (z == 1) ? wk : wv;
    const float* bias = (z == 0) ? bq : (z == 1) ? bk : bv;
    const float scale = (z == 1) ? 0.08838834764831845f : 1.f;  // Dk^-0.5 on k
    const int c = cg * 256 + threadIdx.x;
    const float w0 = w[c * 4], w1 = w[c * 4 + 1], w2 = w[c * 4 + 2], w3 = w[c * 4 + 3];
    const float bs = bias[c];
    float y0 = 0.f, y1 = 0.f, y2 = 0.f;
    if (j > 0) {
        const float* s = scr + ((size_t)(z * 2 + b) * 15 + (j - 1)) * 3 * 1024 + c;
        y0 = s[0]; y1 = s[1024]; y2 = s[2048];
    }
    float* yp = y + ((size_t)b * TSEQ + j * 64) * HID_ + c;
#pragma unroll 4
    for (int t = 0; t < 64; ++t) {
        float y3  = yp[(size_t)t * HID_];
        float acc = fmaf(w0, y0, fmaf(w1, y1, fmaf(w2, y2, fmaf(w3, y3, bs))));
        float sv  = acc * sig_(acc) * scale;
        yp[(size_t)t * HID_] = sv;
        y0 = y1; y1 = y2; y2 = y3;
    }
}

// ---------------- sequential scan, chunked staging + DPP reduces ----------------
#define SCH 16
#define NCH (TSEQ / SCH)
#define NF4 1160                 // float4s per chunk: K 512 | Q 512 | V 128 | A 4 | B 4
#define QOFF 2048
#define VOFF 4096
#define AOFF 4608
#define BOFF 4624
#define CBUF 4640

__global__ __launch_bounds__(256)
void k_scan(const float* __restrict__ qlin, const float* __restrict__ klin,
            const float* __restrict__ vlin, const float* __restrict__ aT,
            const float* __restrict__ bT, float* __restrict__ o)
{
    const int bh  = blockIdx.x >> 2;
    const int rb  = blockIdx.x & 3;
    const int b   = bh >> 3;
    const int h   = bh & 7;
    const int tid = threadIdx.x;
    const int row = tid >> 3;
    const int oct = tid & 7;

    const float* kbase = klin + (size_t)b * TSEQ * HID_ + h * DK;
    const float* qbase = qlin + (size_t)b * TSEQ * HID_ + h * DK;
    const float* vbase = vlin + (size_t)b * TSEQ * HID_ + h * DV + rb * 32;
    const float* ap = aT + (size_t)bh * TSEQ;
    const float* bp = bT + (size_t)bh * TSEQ;

    __shared__ float chunk[2][CBUF];

    const float* srcp[5];
    int strd[5], dof[5];
    bool val[5];
#pragma unroll
    for (int j = 0; j < 5; ++j) {
        const int i4 = j * 256 + tid;
        val[j] = (i4 < NF4);
        dof[j] = i4 * 4;
        const float* s = kbase; int st = 0;
        if (i4 < 512)       { s = kbase + (size_t)(i4 >> 5) * HID_ + ((i4 & 31) << 2); st = SCH * HID_; }
        else if (i4 < 1024) { int m = i4 - 512;  s = qbase + (size_t)(m >> 5) * HID_ + ((m & 31) << 2); st = SCH * HID_; }
        else if (i4 < 1152) { int m = i4 - 1024; s = vbase + (size_t)(m >> 3) * HID_ + ((m & 7) << 2); st = SCH * HID_; }
        else if (i4 < 1156) { s = ap + ((i4 - 1152) << 2); st = SCH; }
        else                { s = bp + ((i4 - 1156) << 2); st = SCH; }
        srcp[j] = s; strd[j] = st;
    }

    float S[16];
#pragma unroll
    for (int i = 0; i < 16; ++i) S[i] = 0.f;

    float4 r[5];
#pragma unroll
    for (int j = 0; j < 5; ++j)
        if (val[j]) r[j] = *(const float4*)(srcp[j]);
#pragma unroll
    for (int j = 0; j < 5; ++j)
        if (val[j]) *(float4*)(&chunk[0][dof[j]]) = r[j];
    __syncthreads();

    float* optr = o + (size_t)bh * TSEQ * DV + rb * 32 + row;

    for (int c = 0; c < NCH; ++c) {
        const int cur = c & 1;
        if (c + 1 < NCH) {      // issue next chunk's loads; held in regs thru compute
#pragma unroll
            for (int j = 0; j < 5; ++j)
                if (val[j]) r[j] = *(const float4*)(srcp[j] + (size_t)(c + 1) * strd[j]);
        }
        const float* cb = chunk[cur];
        const int t0 = c * SCH;
#pragma unroll
        for (int t = 0; t < SCH; ++t) {
            const float4 k0 = *(const float4*)(cb + t * 128 + oct * 16);
            const float4 k1 = *(const float4*)(cb + t * 128 + oct * 16 + 4);
            const float4 k2 = *(const float4*)(cb + t * 128 + oct * 16 + 8);
            const float4 k3 = *(const float4*)(cb + t * 128 + oct * 16 + 12);
            float a0 = fmaf(S[0],  k0.x, fmaf(S[1],  k0.y, fmaf(S[2],  k0.z, S[3]  * k0.w)));
            float a1 = fmaf(S[4],  k1.x, fmaf(S[5],  k1.y, fmaf(S[6],  k1.z, S[7]  * k1.w)));
            float a2 = fmaf(S[8],  k2.x, fmaf(S[9],  k2.y, fmaf(S[10], k2.z, S[11] * k2.w)));
            float a3 = fmaf(S[12], k3.x, fmaf(S[13], k3.y, fmaf(S[14], k3.z, S[15] * k3.w)));
            float sk = (a0 + a1) + (a2 + a3);
            sk = reduce8_dpp(sk);                     // VALU-speed 8-lane reduce
            const float vt  = cb[VOFF + t * 32 + row];
            const float at  = cb[AOFF + t];
            const float btv = cb[BOFF + t];
            const float nc1 = -btv * (sk - vt);
            const float4 q0 = *(const float4*)(cb + QOFF + t * 128 + oct * 16);
            const float4 q1 = *(const float4*)(cb + QOFF + t * 128 + oct * 16 + 4);
            const float4 q2 = *(const float4*)(cb + QOFF + t * 128 + oct * 16 + 8);
            const float4 q3 = *(const float4*)(cb + QOFF + t * 128 + oct * 16 + 12);
            S[0]  = fmaf(at, S[0],  nc1 * k0.x);
            S[1]  = fmaf(at, S[1],  nc1 * k0.y);
            S[2]  = fmaf(at, S[2],  nc1 * k0.z);
            S[3]  = fmaf(at, S[3],  nc1 * k0.w);
            S[4]  = fmaf(at, S[4],  nc1 * k1.x);
            S[5]  = fmaf(at, S[5],  nc1 * k1.y);
            S[6]  = fmaf(at, S[6],  nc1 * k1.z);
            S[7]  = fmaf(at, S[7],  nc1 * k1.w);
            S[8]  = fmaf(at, S[8],  nc1 * k2.x);
            S[9]  = fmaf(at, S[9],  nc1 * k2.y);
            S[10] = fmaf(at, S[10], nc1 * k2.z);
            S[11] = fmaf(at, S[11], nc1 * k2.w);
            S[12] = fmaf(at, S[12], nc1 * k3.x);
            S[13] = fmaf(at, S[13], nc1 * k3.y);
            S[14] = fmaf(at, S[14], nc1 * k3.z);
            S[15] = fmaf(at, S[15], nc1 * k3.w);
            float o0 = fmaf(S[0],  q0.x, fmaf(S[1],  q0.y, fmaf(S[2],  q0.z, S[3]  * q0.w)));
            float o1 = fmaf(S[4],  q1.x, fmaf(S[5],  q1.y, fmaf(S[6],  q1.z, S[7]  * q1.w)));
            float o2 = fmaf(S[8],  q2.x, fmaf(S[9],  q2.y, fmaf(S[10], q2.z, S[11] * q2.w)));
            float o3 = fmaf(S[12], q3.x, fmaf(S[13], q3.y, fmaf(S[14], q3.z, S[15] * q3.w)));
            float opv = (o0 + o1) + (o2 + o3);
            opv = reduce8_dpp(opv);                   // VALU-speed 8-lane reduce
            if (oct == 0) optr[(size_t)(t0 + t) * DV] = opv;
        }
        if (c + 1 < NCH) {
            float* wbf = (float*)chunk[cur ^ 1];
#pragma unroll
            for (int j = 0; j < 5; ++j)
                if (val[j]) *(float4*)(wbf + dof[j]) = r[j];
        }
        __syncthreads();        // one barrier per 16 steps
    }
}

// ---------------- LayerNorm(Dv) + sigmoid gate ----------------
__global__ __launch_bounds__(256)
void k_ln_gate(const float* __restrict__ o, const float* __restrict__ g_lin,
               const float* __restrict__ ln_g, const float* __restrict__ ln_b,
               float* __restrict__ og)
{
    const int idx  = blockIdx.x * 4 + (threadIdx.x >> 6);
    const int lane = threadIdx.x & 63;
    const int h  = idx & 7;
    const int bt = idx >> 3;
    const int b  = bt >> 10;
    const int t  = bt & 1023;
    const float* op = o + ((size_t)(b * NH + h) * TSEQ + t) * DV;
    float2 xv = ((const float2*)op)[lane];
    float s = xv.x + xv.y;
#pragma unroll
    for (int m = 32; m; m >>= 1) s += __shfl_xor(s, m);
    const float mu = s * (1.f / 128.f);
    const float d0 = xv.x - mu, d1 = xv.y - mu;
    float v = d0 * d0 + d1 * d1;
#pragma unroll
    for (int m = 32; m; m >>= 1) v += __shfl_xor(v, m);
    const float inv = rsqrtf(v * (1.f / 128.f) + 1e-5f);
    const int d = lane * 2;
    const float* gp = g_lin + (size_t)bt * HID_ + h * DV;
    const float g0 = sig_(gp[d]), g1 = sig_(gp[d + 1]);
    const float y0 = (d0 * inv * ln_g[d]     + ln_b[d])     * g0;
    const float y1 = (d1 * inv * ln_g[d + 1] + ln_b[d + 1]) * g1;
    ((float2*)(og + (size_t)bt * HID_ + h * DV))[lane] = make_float2(y0, y1);
}

extern "C" void kernel_launch(void* const* d_in, const int* in_sizes, int n_in,
                              void* d_out, int out_size, void* d_ws, size_t ws_size,
                              hipStream_t stream)
{
    const float* x   = (const float*)d_in[0];
    const float* Wq  = (const float*)d_in[1];
    const float* Wk  = (const float*)d_in[2];
    const float* Wv  = (const float*)d_in[3];
    const float* cqw = (const float*)d_in[4];
    const float* cqb = (const float*)d_in[5];
    const float* ckw = (const float*)d_in[6];
    const float* ckb = (const float*)d_in[7];
    const float* cvw = (const float*)d_in[8];
    const float* cvb = (const float*)d_in[9];
    const float* Wa  = (const float*)d_in[10];
    const float* ba  = (const float*)d_in[11];
    const float* Wb  = (const float*)d_in[12];
    const float* bb  = (const float*)d_in[13];
    const float* Wg  = (const float*)d_in[14];
    const float* Wo  = (const float*)d_in[15];
    const float* lng = (const float*)d_in[16];
    const float* lnb = (const float*)d_in[17];
    float* out = (float*)d_out;
    float* ws  = (float*)d_ws;

    float* q_lin = ws;
    float* k_lin = ws + 1 * (size_t)SZf;
    float* v_lin = ws + 2 * (size_t)SZf;
    float* g_lin = ws + 3 * (size_t)SZf;
    float* o_buf = ws + 4 * (size_t)SZf;
    float* aT    = ws + 5 * (size_t)SZf;
    float* bT    = aT + 16 * TSEQ;
    float* og    = ws;

    k_qkvg_gemm<<<dim3(8, 16, 4), 256, 0, stream>>>(x, Wq, Wk, Wv, Wg, ws);
    k_ab<<<ROWS, 64, 0, stream>>>(x, Wa, ba, Wb, bb, aT, bT);
    k_conv_save<<<dim3(15, 2, 3), 256, 0, stream>>>(q_lin, k_lin, v_lin, o_buf);
    k_conv_apply<<<dim3(64, 2, 3), 256, 0, stream>>>(q_lin, k_lin, v_lin, o_buf,
                                                     cqw, cqb, ckw, ckb, cvw, cvb);
    k_scan<<<64, 256, 0, stream>>>(q_lin, k_lin, v_lin, aT, bT, o_buf);
    k_ln_gate<<<4096, 256, 0, stream>>>(o_buf, g_lin, lng, lnb, og);
    k_out_gemm<<<dim3(8, 16), 256, 0, stream>>>(og, Wo, out);
}

// Round 5
// 535.843 us; speedup vs baseline: 2.5634x; 1.4835x over previous
//
#include <hip/hip_runtime.h>

#define TSEQ 1024
#define HID_ 1024
#define NH 8
#define DK 128
#define DV 128
#define ROWS 2048               // B*T
#define SZf (ROWS * HID_)       // floats per [2048,1024] matrix

typedef __attribute__((ext_vector_type(8))) short short8;
typedef __attribute__((ext_vector_type(4))) float f32x4;

__device__ __forceinline__ float sig_(float x) { return 1.f / (1.f + __expf(-x)); }

__device__ __forceinline__ ushort f2bf(float f) {   // RNE f32->bf16
    unsigned int u = __builtin_bit_cast(unsigned int, f);
    u += 0x7FFF + ((u >> 16) & 1);
    return (ushort)(u >> 16);
}
__device__ __forceinline__ unsigned int pk2(float lo, float hi) {
    return (unsigned int)f2bf(lo) | ((unsigned int)f2bf(hi) << 16);
}

// ---- 8-lane butterfly reduce at VALU speed via DPP
template<int CTRL>
__device__ __forceinline__ float dpp_add(float x) {
    int yi = __builtin_amdgcn_update_dpp(0, __builtin_bit_cast(int, x),
                                         CTRL, 0xF, 0xF, true);
    return x + __builtin_bit_cast(float, yi);
}
__device__ __forceinline__ float reduce8_dpp(float x) {
    x = dpp_add<0xB1>(x);
    x = dpp_add<0x4E>(x);
    x = dpp_add<0x141>(x);
    return x;
}

// ---------------- weight transpose+convert: W f32 [K][N] -> WT bf16 [N][K] ----
__global__ __launch_bounds__(256)
void k_wT(const float* __restrict__ s0, const float* __restrict__ s1,
          const float* __restrict__ s2, const float* __restrict__ s3,
          ushort* __restrict__ dst)
{
    const int z = blockIdx.z;
    const float* W = (z == 0) ? s0 : (z == 1) ? s1 : (z == 2) ? s2 : s3;
    ushort* WT = dst + (size_t)z * (1024 * 1024);
    __shared__ float t[64][65];
    const int n0 = blockIdx.x * 64, k0 = blockIdx.y * 64;
    const int rr = threadIdx.x >> 4, cc = threadIdx.x & 15;
#pragma unroll
    for (int i = 0; i < 4; ++i) {
        const int row = i * 16 + rr;
        float4 v = *(const float4*)(W + (size_t)(k0 + row) * 1024 + n0 + cc * 4);
        t[row][cc * 4 + 0] = v.x; t[row][cc * 4 + 1] = v.y;
        t[row][cc * 4 + 2] = v.z; t[row][cc * 4 + 3] = v.w;
    }
    __syncthreads();
#pragma unroll
    for (int i = 0; i < 4; ++i) {
        const int n = i * 16 + rr;
        const int kc = cc * 4;
        ushort4 o;
        o.x = f2bf(t[kc + 0][n]); o.y = f2bf(t[kc + 1][n]);
        o.z = f2bf(t[kc + 2][n]); o.w = f2bf(t[kc + 3][n]);
        *(ushort4*)(WT + (size_t)(n0 + n) * 1024 + k0 + kc) = o;
    }
}

// ---------------- bf16 MFMA GEMM: C[M][1024] = A f32 [M][1024] x BT bf16 [N][K] ----
#define LDSB 40        // bf16 stride: 80B rows, 16B-aligned frags, <=2-way banks
__device__ __forceinline__ void gemm_tile_mfma(const float* __restrict__ A,
                                               const ushort* __restrict__ BT,
                                               float* __restrict__ C,
                                               int brow, int bcol)
{
    __shared__ ushort As[128 * LDSB];
    __shared__ ushort Bs[128 * LDSB];
    const int tid  = threadIdx.x;
    const int lane = tid & 63;
    const int wv   = tid >> 6;
    const int wm   = (wv >> 1) * 64;     // wave row offset
    const int wn   = (wv & 1) * 64;      // wave col offset
    const int l15  = lane & 15;
    const int k8   = (lane >> 4) * 8;    // frag k offset (bf16)
    const int srow = tid >> 1;           // staging row 0..127
    const int skh  = (tid & 1) * 16;     // staging k half

    f32x4 acc[4][4];
#pragma unroll
    for (int i = 0; i < 4; ++i)
#pragma unroll
        for (int j = 0; j < 4; ++j)
#pragma unroll
            for (int e = 0; e < 4; ++e) acc[i][j][e] = 0.f;

    const float*  arow = A  + (size_t)(brow + srow) * 1024 + skh;
    const ushort* brp  = BT + (size_t)(bcol + srow) * 1024 + skh;
    ushort* asw = As + srow * LDSB + skh;
    ushort* bsw = Bs + srow * LDSB + skh;

    for (int k0 = 0; k0 < 1024; k0 += 32) {
        float4 a0 = *(const float4*)(arow + k0);
        float4 a1 = *(const float4*)(arow + k0 + 4);
        float4 a2 = *(const float4*)(arow + k0 + 8);
        float4 a3 = *(const float4*)(arow + k0 + 12);
        uint4 b0 = *(const uint4*)(brp + k0);
        uint4 b1 = *(const uint4*)(brp + k0 + 8);
        uint4 w0, w1;
        w0.x = pk2(a0.x, a0.y); w0.y = pk2(a0.z, a0.w);
        w0.z = pk2(a1.x, a1.y); w0.w = pk2(a1.z, a1.w);
        w1.x = pk2(a2.x, a2.y); w1.y = pk2(a2.z, a2.w);
        w1.z = pk2(a3.x, a3.y); w1.w = pk2(a3.z, a3.w);
        __syncthreads();                 // prev iter's frag reads done
        *(uint4*)(asw)     = w0;
        *(uint4*)(asw + 8) = w1;
        *(uint4*)(bsw)     = b0;
        *(uint4*)(bsw + 8) = b1;
        __syncthreads();
        short8 af[4], bf[4];
#pragma unroll
        for (int i = 0; i < 4; ++i)
            af[i] = *(const short8*)(As + (wm + i * 16 + l15) * LDSB + k8);
#pragma unroll
        for (int j = 0; j < 4; ++j)
            bf[j] = *(const short8*)(Bs + (wn + j * 16 + l15) * LDSB + k8);
#pragma unroll
        for (int i = 0; i < 4; ++i)
#pragma unroll
            for (int j = 0; j < 4; ++j)
                acc[i][j] = __builtin_amdgcn_mfma_f32_16x16x32_bf16(
                    af[i], bf[j], acc[i][j], 0, 0, 0);
    }
    const int l4 = lane >> 4;
#pragma unroll
    for (int i = 0; i < 4; ++i)
#pragma unroll
        for (int j = 0; j < 4; ++j)
#pragma unroll
            for (int r = 0; r < 4; ++r)
                C[(size_t)(brow + wm + i * 16 + l4 * 4 + r) * 1024 +
                  bcol + wn + j * 16 + l15] = acc[i][j][r];
}

__global__ __launch_bounds__(256)
void k_gemm4(const float* __restrict__ A, const ushort* __restrict__ WT,
             float* __restrict__ Cbase)
{
    const ushort* BT = WT + (size_t)blockIdx.z * (1024 * 1024);
    float* C = Cbase + (size_t)blockIdx.z * SZf;
    gemm_tile_mfma(A, BT, C, blockIdx.y * 128, blockIdx.x * 128);
}

__global__ __launch_bounds__(256)
void k_gemm1(const float* __restrict__ A, const ushort* __restrict__ BT,
             float* __restrict__ C)
{
    gemm_tile_mfma(A, BT, C, blockIdx.y * 128, blockIdx.x * 128);
}

// -------- alpha/beta small GEMM + sigmoid; writes TRANSPOSED [bh][t] --------
__global__ __launch_bounds__(64)
void k_ab(const float* __restrict__ x, const float* __restrict__ Wa,
          const float* __restrict__ ba, const float* __restrict__ Wb,
          const float* __restrict__ bb, float* __restrict__ aT,
          float* __restrict__ bT)
{
    const int r = blockIdx.x;           // r = b*1024 + t
    const int lane = threadIdx.x;
    const int b = r >> 10, t = r & 1023;
    const float* xr = x + (size_t)r * HID_;
    float acc[16];
#pragma unroll
    for (int n = 0; n < 16; ++n) acc[n] = 0.f;
    for (int c = lane; c < HID_; c += 64) {
        const float xv = xr[c];
        const float* wa = Wa + c * 8;
        const float* wb = Wb + c * 8;
#pragma unroll
        for (int n = 0; n < 8; ++n) {
            acc[n]     = fmaf(xv, wa[n], acc[n]);
            acc[8 + n] = fmaf(xv, wb[n], acc[8 + n]);
        }
    }
#pragma unroll
    for (int n = 0; n < 16; ++n) {
#pragma unroll
        for (int m = 32; m; m >>= 1) acc[n] += __shfl_xor(acc[n], m);
    }
    if (lane < 8) {
        aT[(size_t)(b * 8 + lane) * TSEQ + t] = sig_(acc[lane] + ba[lane]);
        bT[(size_t)(b * 8 + lane) * TSEQ + t] = sig_(acc[8 + lane] + bb[lane]);
    }
}

// -------- causal depthwise conv K=4 + SiLU (+scale), in-place, T-parallel ----
__global__ __launch_bounds__(256)
void k_conv_save(const float* __restrict__ q, const float* __restrict__ k,
                 const float* __restrict__ v, float* __restrict__ scr)
{
    const int z = blockIdx.z, b = blockIdx.y, j = blockIdx.x + 1;  // j=1..15
    const float* y = (z == 0) ? q : (z == 1) ? k : v;
    float* d = scr + ((size_t)(z * 2 + b) * 15 + (j - 1)) * 3 * 1024;
    const float* s = y + ((size_t)b * TSEQ + j * 64 - 3) * HID_;
    for (int i = threadIdx.x; i < 3 * 1024; i += 256)
        d[i] = s[i];
}

__global__ __launch_bounds__(256)
void k_conv_apply(float* __restrict__ q, float* __restrict__ k, float* __restrict__ v,
                  const float* __restrict__ scr,
                  const float* __restrict__ wq, const float* __restrict__ bq,
                  const float* __restrict__ wk, const float* __restrict__ bk,
                  const float* __restrict__ wv, const float* __restrict__ bv)
{
    const int z = blockIdx.z, b = blockIdx.y;
    const int j = blockIdx.x >> 2, cg = blockIdx.x & 3;
    float* y          = (z == 0) ? q  : (z == 1) ? k  : v;
    const float* w    = (z == 0) ? wq : (z == 1) ? wk : wv;
    const float* bias = (z == 0) ? bq : (z == 1) ? bk : bv;
    const float scale = (z == 1) ? 0.08838834764831845f : 1.f;  // Dk^-0.5 on k
    const int c = cg * 256 + threadIdx.x;
    const float w0 = w[c * 4], w1 = w[c * 4 + 1], w2 = w[c * 4 + 2], w3 = w[c * 4 + 3];
    const float bs = bias[c];
    float y0 = 0.f, y1 = 0.f, y2 = 0.f;
    if (j > 0) {
        const float* s = scr + ((size_t)(z * 2 + b) * 15 + (j - 1)) * 3 * 1024 + c;
        y0 = s[0]; y1 = s[1024]; y2 = s[2048];
    }
    float* yp = y + ((size_t)b * TSEQ + j * 64) * HID_ + c;
#pragma unroll 4
    for (int t = 0; t < 64; ++t) {
        float y3  = yp[(size_t)t * HID_];
        float acc = fmaf(w0, y0, fmaf(w1, y1, fmaf(w2, y2, fmaf(w3, y3, bs))));
        float sv  = acc * sig_(acc) * scale;
        yp[(size_t)t * HID_] = sv;
        y0 = y1; y1 = y2; y2 = y3;
    }
}

// ---------------- sequential scan: chunked staging + swizzled k/q + DPP ------
// swizzle: logical quad q of oct o stored at slot (q + (o>>1))&3 -> the 8 octs'
// float4 reads hit 8 distinct bank quads (was 4-way conflicted).
#define SCH 16
#define NCH (TSEQ / SCH)
#define NF4 1160                 // float4s per chunk: K 512 | Q 512 | V 128 | A 4 | B 4
#define QOFF 2048
#define VOFF 4096
#define AOFF 4608
#define BOFF 4624
#define CBUF 4640

__global__ __launch_bounds__(256)
void k_scan(const float* __restrict__ qlin, const float* __restrict__ klin,
            const float* __restrict__ vlin, const float* __restrict__ aT,
            const float* __restrict__ bT, float* __restrict__ o)
{
    const int bh  = blockIdx.x >> 2;
    const int rb  = blockIdx.x & 3;
    const int b   = bh >> 3;
    const int h   = bh & 7;
    const int tid = threadIdx.x;
    const int row = tid >> 3;
    const int oct = tid & 7;

    const float* kbase = klin + (size_t)b * TSEQ * HID_ + h * DK;
    const float* qbase = qlin + (size_t)b * TSEQ * HID_ + h * DK;
    const float* vbase = vlin + (size_t)b * TSEQ * HID_ + h * DV + rb * 32;
    const float* ap = aT + (size_t)bh * TSEQ;
    const float* bp = bT + (size_t)bh * TSEQ;

    __shared__ float chunk[2][CBUF];

    const float* srcp[5];
    int strd[5], dof[5];
    bool val[5];
#pragma unroll
    for (int j = 0; j < 5; ++j) {
        const int i4 = j * 256 + tid;
        val[j] = (i4 < NF4);
        const float* s = kbase; int st = 0; int d = i4;
        if (i4 < 512) {
            const int t = i4 >> 5, c4 = i4 & 31, os = c4 >> 2, ql = c4 & 3;
            s = kbase + (size_t)t * HID_ + (c4 << 2); st = SCH * HID_;
            d = t * 32 + os * 4 + ((ql + (os >> 1)) & 3);            // swizzled
        } else if (i4 < 1024) {
            const int m = i4 - 512;
            const int t = m >> 5, c4 = m & 31, os = c4 >> 2, ql = c4 & 3;
            s = qbase + (size_t)t * HID_ + (c4 << 2); st = SCH * HID_;
            d = 512 + t * 32 + os * 4 + ((ql + (os >> 1)) & 3);      // swizzled
        } else if (i4 < 1152) {
            const int m = i4 - 1024;
            s = vbase + (size_t)(m >> 3) * HID_ + ((m & 7) << 2); st = SCH * HID_;
        } else if (i4 < 1156) {
            s = ap + ((i4 - 1152) << 2); st = SCH;
        } else {
            s = bp + ((i4 - 1156) << 2); st = SCH;
        }
        srcp[j] = s; strd[j] = st; dof[j] = d * 4;
    }

    float S[16];
#pragma unroll
    for (int i = 0; i < 16; ++i) S[i] = 0.f;

    float4 r[5];
#pragma unroll
    for (int j = 0; j < 5; ++j)
        if (val[j]) r[j] = *(const float4*)(srcp[j]);
#pragma unroll
    for (int j = 0; j < 5; ++j)
        if (val[j]) *(float4*)(&chunk[0][dof[j]]) = r[j];
    __syncthreads();

    float* optr = o + (size_t)bh * TSEQ * DV + rb * 32 + row;
    const int swz = oct >> 1;

    for (int c = 0; c < NCH; ++c) {
        const int cur = c & 1;
        if (c + 1 < NCH) {      // issue next chunk's loads; held in regs thru compute
#pragma unroll
            for (int j = 0; j < 5; ++j)
                if (val[j]) r[j] = *(const float4*)(srcp[j] + (size_t)(c + 1) * strd[j]);
        }
        const float* cb = chunk[cur];
        // 4 swizzled base pointers; inner reads use immediate t*512B offsets
        const float* p0 = cb + oct * 16 + (((0 + swz) & 3) << 2);
        const float* p1 = cb + oct * 16 + (((1 + swz) & 3) << 2);
        const float* p2 = cb + oct * 16 + (((2 + swz) & 3) << 2);
        const float* p3 = cb + oct * 16 + (((3 + swz) & 3) << 2);
        const int t0 = c * SCH;
#pragma unroll
        for (int t = 0; t < SCH; ++t) {
            const float4 k0 = *(const float4*)(p0 + t * 128);
            const float4 k1 = *(const float4*)(p1 + t * 128);
            const float4 k2 = *(const float4*)(p2 + t * 128);
            const float4 k3 = *(const float4*)(p3 + t * 128);
            float a0 = fmaf(S[0],  k0.x, fmaf(S[1],  k0.y, fmaf(S[2],  k0.z, S[3]  * k0.w)));
            float a1 = fmaf(S[4],  k1.x, fmaf(S[5],  k1.y, fmaf(S[6],  k1.z, S[7]  * k1.w)));
            float a2 = fmaf(S[8],  k2.x, fmaf(S[9],  k2.y, fmaf(S[10], k2.z, S[11] * k2.w)));
            float a3 = fmaf(S[12], k3.x, fmaf(S[13], k3.y, fmaf(S[14], k3.z, S[15] * k3.w)));
            float sk = (a0 + a1) + (a2 + a3);
            sk = reduce8_dpp(sk);
            const float vt  = cb[VOFF + t * 32 + row];
            const float at  = cb[AOFF + t];
            const float btv = cb[BOFF + t];
            const float nc1 = -btv * (sk - vt);
            const float4 q0 = *(const float4*)(p0 + QOFF + t * 128);
            const float4 q1 = *(const float4*)(p1 + QOFF + t * 128);
            const float4 q2 = *(const float4*)(p2 + QOFF + t * 128);
            const float4 q3 = *(const float4*)(p3 + QOFF + t * 128);
            S[0]  = fmaf(at, S[0],  nc1 * k0.x);
            S[1]  = fmaf(at, S[1],  nc1 * k0.y);
            S[2]  = fmaf(at, S[2],  nc1 * k0.z);
            S[3]  = fmaf(at, S[3],  nc1 * k0.w);
            S[4]  = fmaf(at, S[4],  nc1 * k1.x);
            S[5]  = fmaf(at, S[5],  nc1 * k1.y);
            S[6]  = fmaf(at, S[6],  nc1 * k1.z);
            S[7]  = fmaf(at, S[7],  nc1 * k1.w);
            S[8]  = fmaf(at, S[8],  nc1 * k2.x);
            S[9]  = fmaf(at, S[9],  nc1 * k2.y);
            S[10] = fmaf(at, S[10], nc1 * k2.z);
            S[11] = fmaf(at, S[11], nc1 * k2.w);
            S[12] = fmaf(at, S[12], nc1 * k3.x);
            S[13] = fmaf(at, S[13], nc1 * k3.y);
            S[14] = fmaf(at, S[14], nc1 * k3.z);
            S[15] = fmaf(at, S[15], nc1 * k3.w);
            float o0 = fmaf(S[0],  q0.x, fmaf(S[1],  q0.y, fmaf(S[2],  q0.z, S[3]  * q0.w)));
            float o1 = fmaf(S[4],  q1.x, fmaf(S[5],  q1.y, fmaf(S[6],  q1.z, S[7]  * q1.w)));
            float o2 = fmaf(S[8],  q2.x, fmaf(S[9],  q2.y, fmaf(S[10], q2.z, S[11] * q2.w)));
            float o3 = fmaf(S[12], q3.x, fmaf(S[13], q3.y, fmaf(S[14], q3.z, S[15] * q3.w)));
            float opv = (o0 + o1) + (o2 + o3);
            opv = reduce8_dpp(opv);
            if (oct == 0) optr[(size_t)(t0 + t) * DV] = opv;
        }
        if (c + 1 < NCH) {
            float* wbf = (float*)chunk[cur ^ 1];
#pragma unroll
            for (int j = 0; j < 5; ++j)
                if (val[j]) *(float4*)(wbf + dof[j]) = r[j];
        }
        __syncthreads();        // one barrier per 16 steps
    }
}

// ---------------- LayerNorm(Dv) + sigmoid gate ----------------
__global__ __launch_bounds__(256)
void k_ln_gate(const float* __restrict__ o, const float* __restrict__ g_lin,
               const float* __restrict__ ln_g, const float* __restrict__ ln_b,
               float* __restrict__ og)
{
    const int idx  = blockIdx.x * 4 + (threadIdx.x >> 6);
    const int lane = threadIdx.x & 63;
    const int h  = idx & 7;
    const int bt = idx >> 3;
    const int b  = bt >> 10;
    const int t  = bt & 1023;
    const float* op = o + ((size_t)(b * NH + h) * TSEQ + t) * DV;
    float2 xv = ((const float2*)op)[lane];
    float s = xv.x + xv.y;
#pragma unroll
    for (int m = 32; m; m >>= 1) s += __shfl_xor(s, m);
    const float mu = s * (1.f / 128.f);
    const float d0 = xv.x - mu, d1 = xv.y - mu;
    float v = d0 * d0 + d1 * d1;
#pragma unroll
    for (int m = 32; m; m >>= 1) v += __shfl_xor(v, m);
    const float inv = rsqrtf(v * (1.f / 128.f) + 1e-5f);
    const int d = lane * 2;
    const float* gp = g_lin + (size_t)bt * HID_ + h * DV;
    const float g0 = sig_(gp[d]), g1 = sig_(gp[d + 1]);
    const float y0 = (d0 * inv * ln_g[d]     + ln_b[d])     * g0;
    const float y1 = (d1 * inv * ln_g[d + 1] + ln_b[d + 1]) * g1;
    ((float2*)(og + (size_t)bt * HID_ + h * DV))[lane] = make_float2(y0, y1);
}

extern "C" void kernel_launch(void* const* d_in, const int* in_sizes, int n_in,
                              void* d_out, int out_size, void* d_ws, size_t ws_size,
                              hipStream_t stream)
{
    const float* x   = (const float*)d_in[0];
    const float* Wq  = (const float*)d_in[1];
    const float* Wk  = (const float*)d_in[2];
    const float* Wv  = (const float*)d_in[3];
    const float* cqw = (const float*)d_in[4];
    const float* cqb = (const float*)d_in[5];
    const float* ckw = (const float*)d_in[6];
    const float* ckb = (const float*)d_in[7];
    const float* cvw = (const float*)d_in[8];
    const float* cvb = (const float*)d_in[9];
    const float* Wa  = (const float*)d_in[10];
    const float* ba  = (const float*)d_in[11];
    const float* Wb  = (const float*)d_in[12];
    const float* bb  = (const float*)d_in[13];
    const float* Wg  = (const float*)d_in[14];
    const float* Wo  = (const float*)d_in[15];
    const float* lng = (const float*)d_in[16];
    const float* lnb = (const float*)d_in[17];
    float* out = (float*)d_out;
    float* ws  = (float*)d_ws;

    float* q_lin = ws;                       // gemm out -> conv'd in place -> og
    float* k_lin = ws + 1 * (size_t)SZf;     //              -> WoT (after scan)
    float* v_lin = ws + 2 * (size_t)SZf;
    float* g_lin = ws + 3 * (size_t)SZf;
    float* o_buf = ws + 4 * (size_t)SZf;     // WT4 -> conv scratch -> scan out
    float* aT    = ws + 5 * (size_t)SZf;
    float* bT    = aT + 16 * TSEQ;
    float* og    = ws;

    ushort* WT4 = (ushort*)o_buf;            // 4 x 1M bf16 = 8MB, dead after gemm4
    ushort* WoT = (ushort*)k_lin;            // written after scan, dead after gemm1

    k_wT<<<dim3(16, 16, 4), 256, 0, stream>>>(Wq, Wk, Wv, Wg, WT4);
    k_gemm4<<<dim3(8, 16, 4), 256, 0, stream>>>(x, WT4, ws);
    k_ab<<<ROWS, 64, 0, stream>>>(x, Wa, ba, Wb, bb, aT, bT);
    k_conv_save<<<dim3(15, 2, 3), 256, 0, stream>>>(q_lin, k_lin, v_lin, o_buf);
    k_conv_apply<<<dim3(64, 2, 3), 256, 0, stream>>>(q_lin, k_lin, v_lin, o_buf,
                                                     cqw, cqb, ckw, ckb, cvw, cvb);
    k_scan<<<64, 256, 0, stream>>>(q_lin, k_lin, v_lin, aT, bT, o_buf);
    k_wT<<<dim3(16, 16, 1), 256, 0, stream>>>(Wo, Wo, Wo, Wo, WoT);
    k_ln_gate<<<4096, 256, 0, stream>>>(o_buf, g_lin, lng, lnb, og);
    k_gemm1<<<dim3(8, 16), 256, 0, stream>>>(og, WoT, out);
}